// Round 1
// baseline (366.638 us; speedup 1.0000x reference)
//
#include <hip/hip_runtime.h>
#include <math.h>

#define Lc 128
#define Rc 1024
#define Pc 8
#define Ec 64
#define Fc 64

// tiling
#define LT 32   // l rows per block
#define RT 64   // r rows per block
#define ECH 8   // e per block (e-chunk)
#define LPER 8  // l per thread (LT / 4 lane-groups)

// exp(-((d-mu)/sigma)^2) = exp2(-(C*(d-mu))^2), C = (1/0.15625)*sqrt(log2(e))
#define CSCALE 7.68718341623328f
#define MU_STEP 0.15873015873015873f  // 10/63

__global__ __launch_bounds__(256, 2)
void ff_main(const float* __restrict__ lig_feat,
             const float* __restrict__ rec_feat,
             const float* __restrict__ lig_coords,
             const float* __restrict__ rec_coords,
             float* __restrict__ partial)
{
    __shared__ float4 rec_lds[RT * 16];   // XOR-swizzled columns
    __shared__ float4 lig_lds[LT * 16];   // linear (broadcast reads)
    __shared__ float  lc[Pc][LT][3];
    __shared__ float  wsum[4][Pc];

    const int tid = threadIdx.x;
    const int rr  = tid & 63;   // r within tile (lane)
    const int lg  = tid >> 6;   // wave id = l-group

    const int r0 = blockIdx.x * RT;   // 16 r-tiles
    const int l0 = blockIdx.y * LT;   // 4 l-tiles
    const int e0 = blockIdx.z * ECH;  // 8 e-chunks

    // stage lig coords for this l-tile: 8 poses x 32 l x 3 = 768 floats
    for (int i = tid; i < Pc * LT * 3; i += 256) {
        int p   = i / (LT * 3);
        int rem = i - p * (LT * 3);
        int ll  = rem / 3;
        int c   = rem - ll * 3;
        lc[p][ll][c] = lig_coords[((size_t)p * Lc + l0 + ll) * 3 + c];
    }

    const int   r   = r0 + rr;
    const float rcx = rec_coords[r * 3 + 0];
    const float rcy = rec_coords[r * 3 + 1];
    const float rcz = rec_coords[r * 3 + 2];

    __syncthreads();

    // scaled distances dsc[p][k] = C * dist(p, l0+lg*8+k, r)
    float dsc[Pc][LPER];
    #pragma unroll
    for (int k = 0; k < LPER; ++k) {
        const int ll = lg * LPER + k;
        #pragma unroll
        for (int p = 0; p < Pc; ++p) {
            float dx = lc[p][ll][0] - rcx;
            float dy = lc[p][ll][1] - rcy;
            float dz = lc[p][ll][2] - rcz;
            dsc[p][k] = sqrtf(dx * dx + dy * dy + dz * dz) * CSCALE;
        }
    }

    float us[Pc];
    #pragma unroll
    for (int p = 0; p < Pc; ++p) us[p] = 0.f;

    const int fr   = tid & 15;  // float4 column
    const int row0 = tid >> 4;  // 0..15

    for (int el = 0; el < ECH; ++el) {
        const int e = e0 + el;
        __syncthreads();
        // stage rec rows (swizzled): 64 rows x 16 float4
        #pragma unroll
        for (int j = 0; j < 4; ++j) {
            const int row  = row0 + 16 * j;
            const int slot = fr ^ (row & 15);
            rec_lds[row * 16 + slot] =
                *(const float4*)(rec_feat + ((size_t)(r0 + row) * Ec + e) * Fc + fr * 4);
        }
        // stage lig rows (linear): 32 rows x 16 float4
        #pragma unroll
        for (int j = 0; j < 2; ++j) {
            const int row = row0 + 16 * j;
            lig_lds[row * 16 + fr] =
                *(const float4*)(lig_feat + ((size_t)(l0 + row) * Ec + e) * Fc + fr * 4);
        }
        __syncthreads();

        // rec row -> registers (unswizzle): conflict-free (16 distinct cols/group)
        float4 rv[16];
        #pragma unroll
        for (int f4 = 0; f4 < 16; ++f4)
            rv[f4] = rec_lds[rr * 16 + (f4 ^ (rr & 15))];

        const float musc = (float)e * (MU_STEP * CSCALE);

        #pragma unroll
        for (int k = 0; k < LPER; ++k) {
            const float4* lrow = &lig_lds[(lg * LPER + k) * 16];
            float ax = 0.f, ay = 0.f, az = 0.f, aw = 0.f;
            #pragma unroll
            for (int f4 = 0; f4 < 16; ++f4) {
                float4 lv = lrow[f4];   // full-wave broadcast
                ax += lv.x * rv[f4].x;
                ay += lv.y * rv[f4].y;
                az += lv.z * rv[f4].z;
                aw += lv.w * rv[f4].w;
            }
            const float a = (ax + ay) + (az + aw);  // atn[l, r, e]
            #pragma unroll
            for (int p = 0; p < Pc; ++p) {
                float t = dsc[p][k] - musc;
                us[p] += a * __builtin_amdgcn_exp2f(-t * t);
            }
        }
    }

    // wave butterfly reduce
    #pragma unroll
    for (int p = 0; p < Pc; ++p) {
        float v = us[p];
        #pragma unroll
        for (int off = 32; off >= 1; off >>= 1)
            v += __shfl_xor(v, off, 64);
        us[p] = v;
    }
    if (rr == 0) {
        #pragma unroll
        for (int p = 0; p < Pc; ++p) wsum[lg][p] = us[p];
    }
    __syncthreads();
    if (tid == 0) {
        const int bid = (blockIdx.z * gridDim.y + blockIdx.y) * gridDim.x + blockIdx.x;
        #pragma unroll
        for (int p = 0; p < Pc; ++p)
            partial[bid * Pc + p] = wsum[0][p] + wsum[1][p] + wsum[2][p] + wsum[3][p];
    }
}

// reduce 512 block-partials x 8 poses -> 8 outputs
__global__ void ff_reduce(const float* __restrict__ partial, float* __restrict__ out)
{
    const int w    = threadIdx.x >> 6;  // pose = wave id
    const int lane = threadIdx.x & 63;
    float v = 0.f;
    #pragma unroll
    for (int j = 0; j < 8; ++j)
        v += partial[(size_t)(lane + 64 * j) * Pc + w];
    #pragma unroll
    for (int off = 32; off >= 1; off >>= 1)
        v += __shfl_xor(v, off, 64);
    if (lane == 0) out[w] = 0.1f * v;
}

extern "C" void kernel_launch(void* const* d_in, const int* in_sizes, int n_in,
                              void* d_out, int out_size, void* d_ws, size_t ws_size,
                              hipStream_t stream)
{
    const float* lig_feat   = (const float*)d_in[0];
    const float* rec_feat   = (const float*)d_in[1];
    const float* lig_coords = (const float*)d_in[2];
    const float* rec_coords = (const float*)d_in[3];
    float* out     = (float*)d_out;
    float* partial = (float*)d_ws;   // 512 * 8 * 4 = 16 KB

    dim3 grid(Rc / RT, Lc / LT, Ec / ECH);  // 16 x 4 x 8 = 512 blocks
    ff_main<<<grid, 256, 0, stream>>>(lig_feat, rec_feat, lig_coords, rec_coords, partial);
    ff_reduce<<<1, 512, 0, stream>>>(partial, out);
}

// Round 2
// 102.616 us; speedup vs baseline: 3.5729x; 3.5729x over previous
//
#include <hip/hip_runtime.h>
#include <math.h>

#define Lc 128
#define Rc 1024
#define Pc 8
#define Ec 64
#define Fc 64

// tiling
#define RT 64    // r per block (= lane)
#define LPER 4   // l per wave
#define NWAVE 4
#define LT (LPER * NWAVE)  // 16 l per block
#define ECH 8    // e per block
#define NBLK ((Rc / RT) * (Lc / LT) * (Ec / ECH))  // 16*8*8 = 1024

// exp(-((d-mu)/sigma)^2) = exp2(-(C*(d-mu))^2), C = (1/0.15625)*sqrt(log2(e))
#define CSCALE 7.68718341623328f
#define MU_STEP 0.15873015873015873f  // 10/63

__global__ __launch_bounds__(256, 4)
void ff_main(const float* __restrict__ lig_feat,
             const float* __restrict__ rec_feat,
             const float* __restrict__ lig_coords,
             const float* __restrict__ rec_coords,
             float* __restrict__ partial)
{
    __shared__ float wsum[NWAVE][Pc];

    const int tid = threadIdx.x;
    const int rr  = tid & 63;
    const int lg  = tid >> 6;

    const int r0 = blockIdx.x * RT;
    const int l0 = blockIdx.y * LT;
    const int e0 = blockIdx.z * ECH;

    const int r = r0 + rr;
    const float rcx = rec_coords[r * 3 + 0];
    const float rcy = rec_coords[r * 3 + 1];
    const float rcz = rec_coords[r * 3 + 2];

    // wave-uniform l base -> scalar loads for everything lig-side
    const int lbase = __builtin_amdgcn_readfirstlane(l0 + lg * LPER);

    // scaled distances: dsc[p][k] = C * dist(p, lbase+k, r)   (32 VGPRs)
    float dsc[Pc][LPER];
    #pragma unroll
    for (int k = 0; k < LPER; ++k) {
        #pragma unroll
        for (int p = 0; p < Pc; ++p) {
            const float* lcp = lig_coords + ((size_t)p * Lc + lbase + k) * 3;
            float dx = lcp[0] - rcx;
            float dy = lcp[1] - rcy;
            float dz = lcp[2] - rcz;
            dsc[p][k] = sqrtf(dx * dx + dy * dy + dz * dz) * CSCALE;
        }
    }

    float us[Pc];
    #pragma unroll
    for (int p = 0; p < Pc; ++p) us[p] = 0.f;

    for (int el = 0; el < ECH; ++el) {
        const int e = e0 + el;

        // this lane's rec row -> 16 float4 registers (256 B contiguous)
        const float4* rrow = (const float4*)(rec_feat + ((size_t)r * Ec + e) * Fc);
        float4 rv[16];
        #pragma unroll
        for (int f4 = 0; f4 < 16; ++f4) rv[f4] = rrow[f4];

        const float musc = (float)e * (MU_STEP * CSCALE);

        #pragma unroll
        for (int k = 0; k < LPER; ++k) {
            // wave-uniform lig row -> s_load, consumed as SGPR operand in v_fmac
            const float* lrow = lig_feat + ((size_t)(lbase + k) * Ec + e) * Fc;
            float a0 = 0.f, a1 = 0.f, a2 = 0.f, a3 = 0.f;
            #pragma unroll
            for (int f4 = 0; f4 < 16; ++f4) {
                a0 += lrow[4 * f4 + 0] * rv[f4].x;
                a1 += lrow[4 * f4 + 1] * rv[f4].y;
                a2 += lrow[4 * f4 + 2] * rv[f4].z;
                a3 += lrow[4 * f4 + 3] * rv[f4].w;
            }
            const float a = (a0 + a1) + (a2 + a3);  // atn[lbase+k, r, e]
            #pragma unroll
            for (int p = 0; p < Pc; ++p) {
                float t = dsc[p][k] - musc;
                us[p] += a * __builtin_amdgcn_exp2f(-(t * t));
            }
        }
    }

    // wave butterfly reduce (over the 64 r's)
    #pragma unroll
    for (int p = 0; p < Pc; ++p) {
        float v = us[p];
        #pragma unroll
        for (int off = 32; off >= 1; off >>= 1)
            v += __shfl_xor(v, off, 64);
        us[p] = v;
    }
    if (rr == 0) {
        #pragma unroll
        for (int p = 0; p < Pc; ++p) wsum[lg][p] = us[p];
    }
    __syncthreads();
    if (tid == 0) {
        const int bid = (blockIdx.z * gridDim.y + blockIdx.y) * gridDim.x + blockIdx.x;
        #pragma unroll
        for (int p = 0; p < Pc; ++p)
            partial[bid * Pc + p] = wsum[0][p] + wsum[1][p] + wsum[2][p] + wsum[3][p];
    }
}

// reduce NBLK block-partials x 8 poses -> 8 outputs
__global__ void ff_reduce(const float* __restrict__ partial, float* __restrict__ out)
{
    const int w    = threadIdx.x >> 6;  // pose = wave id (8 waves)
    const int lane = threadIdx.x & 63;
    float v = 0.f;
    #pragma unroll
    for (int j = 0; j < NBLK / 64; ++j)
        v += partial[(size_t)(lane + 64 * j) * Pc + w];
    #pragma unroll
    for (int off = 32; off >= 1; off >>= 1)
        v += __shfl_xor(v, off, 64);
    if (lane == 0) out[w] = 0.1f * v;
}

extern "C" void kernel_launch(void* const* d_in, const int* in_sizes, int n_in,
                              void* d_out, int out_size, void* d_ws, size_t ws_size,
                              hipStream_t stream)
{
    const float* lig_feat   = (const float*)d_in[0];
    const float* rec_feat   = (const float*)d_in[1];
    const float* lig_coords = (const float*)d_in[2];
    const float* rec_coords = (const float*)d_in[3];
    float* out     = (float*)d_out;
    float* partial = (float*)d_ws;   // NBLK * 8 * 4 = 32 KB

    dim3 grid(Rc / RT, Lc / LT, Ec / ECH);  // 16 x 8 x 8 = 1024 blocks
    ff_main<<<grid, 256, 0, stream>>>(lig_feat, rec_feat, lig_coords, rec_coords, partial);
    ff_reduce<<<1, 512, 0, stream>>>(partial, out);
}

// Round 3
// 66.607 us; speedup vs baseline: 5.5045x; 1.5406x over previous
//
#include <hip/hip_runtime.h>
#include <math.h>

#define Lc 128
#define Rc 1024
#define Pc 8
#define Ec 64
#define Fc 64

#define RT 64          // r per block (= lane)
#define LT 8           // l per block
#define NBLK ((Rc / RT) * (Lc / LT))   // 16 * 16 = 256 blocks

// exp(-((d-mu)/sigma)^2) = exp2(-(C*(d-mu))^2), C = (1/0.15625)*sqrt(log2(e))
#define CSCALE   7.68718341623328f
#define MU_STEP  0.15873015873015873f   // 10/63
#define INV_STEP 6.3f                   // 63/10
#define MUC      (MU_STEP * CSCALE)

__global__ __launch_bounds__(1024, 4)
void ff_fused(const float* __restrict__ lig_feat,
              const float* __restrict__ rec_feat,
              const float* __restrict__ lig_coords,
              const float* __restrict__ rec_coords,
              float* __restrict__ partial)
{
    // dynamic: atn tile [LT][64 e][64 r] f32 = 128 KB
    extern __shared__ float atn_lds[];
    // static: rec staging [2 eoff][64 r][8 float4-slots] = 16 KB (f-half of an e-pair)
    __shared__ float4 staged[2 * 64 * 8];

    const int tid = threadIdx.x;
    const int rr  = tid & 63;
    const int w   = __builtin_amdgcn_readfirstlane(tid >> 6);  // wave id 0..15

    // XCD-chunked block swizzle: each XCD owns 2 consecutive r-tiles (rec slice 2 MB, L2-resident)
    const int bid  = blockIdx.x;
    const int slot = bid >> 3;
    const int rt   = (bid & 7) * 2 + (slot >> 4);
    const int lt   = slot & 15;
    const int r0   = rt * RT;
    const int l0   = lt * LT;

    // phase-1 wave roles: l = w&7, eoff = w>>3 (which e of the staged pair)
    const int lw   = w & 7;
    const int eoff = w >> 3;

    const int r   = r0 + rr;
    const float rcx = rec_coords[r * 3 + 0];
    const float rcy = rec_coords[r * 3 + 1];
    const float rcz = rec_coords[r * 3 + 2];

    // staging thread roles: one dwordx4 per thread per iter (coalesced)
    const int f4s   = tid & 7;
    const int rrs   = (tid >> 3) & 63;
    const int eoffs = tid >> 9;
    const int sidx  = (eoffs * 64 + rrs) * 8 + (f4s ^ (rrs & 7));  // XOR slot swizzle
    const float* gbase = rec_feat + (size_t)(r0 + rrs) * (Ec * Fc);

    // precomputed swizzled read indices (loop-invariant)
    int rd8[8];
    #pragma unroll
    for (int f4 = 0; f4 < 8; ++f4)
        rd8[f4] = (eoff * 64 + rr) * 8 + (f4 ^ (rr & 7));

    // ---- prologue: stage iter 0 (e = eoffs, f-half 0) ----
    {
        float4 pf = *(const float4*)(gbase + (size_t)eoffs * Fc + f4s * 4);
        staged[sidx] = pf;
    }
    __syncthreads();

    // ---- phase 1: build atn[lw][e][rr] ----
    float a0 = 0.f, a1 = 0.f, a2 = 0.f, a3 = 0.f;
    const int atn_base = lw * 4096 + eoff * 64 + rr;   // + ep*128 per e-pair

    for (int it = 0; it < 64; ++it) {
        const int ep = it >> 1;
        const int fh = it & 1;
        const int e  = 2 * ep + eoff;
        const float* lrowh = lig_feat + ((size_t)(l0 + lw) * Ec + e) * Fc + fh * 32;

        // issue next iter's global load early (hides HBM/L2 latency under compute)
        float4 pf2;
        const int nit = it + 1;
        if (nit < 64) {
            const int ne = 2 * (nit >> 1) + eoffs;
            pf2 = *(const float4*)(gbase + (size_t)ne * Fc + (nit & 1) * 32 + f4s * 4);
        }

        // dot f-half: 8 x ds_read_b128 (2-way = free) x 4 fmac with SGPR lig operand
        #pragma unroll
        for (int f4 = 0; f4 < 8; ++f4) {
            const float4 rv = staged[rd8[f4]];
            a0 = fmaf(lrowh[f4 * 4 + 0], rv.x, a0);
            a1 = fmaf(lrowh[f4 * 4 + 1], rv.y, a1);
            a2 = fmaf(lrowh[f4 * 4 + 2], rv.z, a2);
            a3 = fmaf(lrowh[f4 * 4 + 3], rv.w, a3);
        }
        if (fh) {
            atn_lds[atn_base + ep * 128] = (a0 + a1) + (a2 + a3);  // bank=rr: conflict-free
            a0 = a1 = a2 = a3 = 0.f;
        }
        __syncthreads();                 // all reads of staged done
        if (nit < 64) staged[sidx] = pf2;
        __syncthreads();                 // staged pair ready
    }

    // ---- phase 2: windowed RBF accumulation ----
    // wave w: l = w&7, pose-half = w>>3; lane = r
    const int ph = w >> 3;
    float us[4];

    #pragma unroll
    for (int pi = 0; pi < 4; ++pi) {
        const int p = ph * 4 + pi;
        const float* lcp = lig_coords + ((size_t)p * Lc + l0 + lw) * 3;  // uniform -> scalar
        const float dx = lcp[0] - rcx;
        const float dy = lcp[1] - rcy;
        const float dz = lcp[2] - rcz;
        const float d  = sqrtf(dx * dx + dy * dy + dz * dz);

        // 16-wide aligned e-window centered near d/step (covers >= 3.5 sigma both sides)
        int xi = (int)(d * INV_STEP + 0.5f) - 8;
        xi = xi < 0 ? 0 : (xi > 48 ? 48 : xi);
        xi &= ~3;
        const float t0 = fmaf(-(float)xi, MUC, d * CSCALE);
        const int   b2 = lw * 4096 + xi * 64 + rr;     // bank=rr: conflict-free

        float usp = 0.f;
        #pragma unroll
        for (int j = 0; j < 16; ++j) {
            const float aj = atn_lds[b2 + j * 64];     // ds_read_b32 offset:j*256
            const float t  = t0 - (float)j * MUC;
            usp = fmaf(aj, __builtin_amdgcn_exp2f(-(t * t)), usp);
        }
        us[pi] = usp;
    }

    // ---- reduce: butterfly over lanes, then across waves ----
    float* wred = (float*)staged;   // reuse staging LDS
    #pragma unroll
    for (int pi = 0; pi < 4; ++pi) {
        float v = us[pi];
        #pragma unroll
        for (int off = 32; off >= 1; off >>= 1)
            v += __shfl_xor(v, off, 64);
        if (rr == 0) wred[w * 4 + pi] = v;
    }
    __syncthreads();
    if (tid < 8) {
        const int phh = tid >> 2;
        float s = 0.f;
        #pragma unroll
        for (int k = 0; k < 8; ++k)
            s += wred[(phh * 8 + k) * 4 + (tid & 3)];
        partial[(size_t)bid * Pc + tid] = s;
    }
}

// reduce NBLK block-partials x 8 poses -> 8 outputs
__global__ void ff_reduce(const float* __restrict__ partial, float* __restrict__ out)
{
    const int w    = threadIdx.x >> 6;  // pose = wave id (8 waves)
    const int lane = threadIdx.x & 63;
    float v = 0.f;
    #pragma unroll
    for (int j = 0; j < NBLK / 64; ++j)
        v += partial[(size_t)(lane + 64 * j) * Pc + w];
    #pragma unroll
    for (int off = 32; off >= 1; off >>= 1)
        v += __shfl_xor(v, off, 64);
    if (lane == 0) out[w] = 0.1f * v;
}

extern "C" void kernel_launch(void* const* d_in, const int* in_sizes, int n_in,
                              void* d_out, int out_size, void* d_ws, size_t ws_size,
                              hipStream_t stream)
{
    const float* lig_feat   = (const float*)d_in[0];
    const float* rec_feat   = (const float*)d_in[1];
    const float* lig_coords = (const float*)d_in[2];
    const float* rec_coords = (const float*)d_in[3];
    float* out     = (float*)d_out;
    float* partial = (float*)d_ws;   // NBLK * 8 * 4 = 8 KB

    static int attr_set = 0;
    if (!attr_set) {
        (void)hipFuncSetAttribute((const void*)ff_fused,
                                  hipFuncAttributeMaxDynamicSharedMemorySize, 131072);
        attr_set = 1;
    }

    ff_fused<<<NBLK, 1024, 131072, stream>>>(lig_feat, rec_feat, lig_coords, rec_coords, partial);
    ff_reduce<<<1, 512, 0, stream>>>(partial, out);
}